// Round 6
// baseline (199.869 us; speedup 1.0000x reference)
//
#include <hip/hip_runtime.h>
#include <hip/hip_bf16.h>

// out[n] = b + e_x[n] * sum_m exp(2*GAMMA*dot(x_n,y_m)) * c[m]
// n=16384, m=8192, d=512.
// Round 6: A-resident GEMM, LDS-read-optimized. r5 was LDS-read-bound
// (0.75 reads/MFMA + 1024B-stride bank conflicts). Now: wave tile 64x64
// (0.5 reads/MFMA), and every 1KB LDS block stored K-MAJOR (granule =
// kslot*16 + row') so fragment reads are base+lane*16 -> conflict-free by
// construction (no swizzle math). Permutation applied on per-lane global
// source of global_load_lds (linear LDS dest).
// LDS: A 128KB resident (16 kchunk x 8 rowblock x 1KB) + B 2x16KB dbuf = 160KB.
//
// Workspace: Xb bf16[16384*512] @0, Yb bf16[8192*512] @16777216,
//            ex f32[16384] @25165824, cw f32[8192] @25231360.

#define GAMMA 0.002f

typedef __bf16 bf16x8 __attribute__((ext_vector_type(8)));
typedef float  f32x4  __attribute__((ext_vector_type(4)));
typedef __attribute__((address_space(3))) void lds_void_t;
typedef __attribute__((address_space(1))) const void gl_void_t;

// ---------------- prep: f32 -> bf16 + exp(-gamma*||row||^2) (xW==nullptr)
// or c[m] = exp(-gamma*||row||^2)*W[m]
__global__ __launch_bounds__(256) void prep_kernel(const float* __restrict__ src,
                                                   __bf16* __restrict__ dst,
                                                   float* __restrict__ fac,
                                                   const float* __restrict__ xW,
                                                   int nrows) {
    const int wid  = threadIdx.x >> 6;
    const int lane = threadIdx.x & 63;
    const int row  = blockIdx.x * 4 + wid;
    if (row >= nrows) return;
    const float4* s = reinterpret_cast<const float4*>(src + (size_t)row * 512);
    float4 v0 = s[lane * 2];
    float4 v1 = s[lane * 2 + 1];
    float acc = v0.x * v0.x + v0.y * v0.y + v0.z * v0.z + v0.w * v0.w
              + v1.x * v1.x + v1.y * v1.y + v1.z * v1.z + v1.w * v1.w;
    bf16x8 o;
    o[0] = (__bf16)v0.x; o[1] = (__bf16)v0.y; o[2] = (__bf16)v0.z; o[3] = (__bf16)v0.w;
    o[4] = (__bf16)v1.x; o[5] = (__bf16)v1.y; o[6] = (__bf16)v1.z; o[7] = (__bf16)v1.w;
    *reinterpret_cast<bf16x8*>(dst + (size_t)row * 512 + lane * 8) = o;
#pragma unroll
    for (int off = 32; off >= 1; off >>= 1) acc += __shfl_xor(acc, off, 64);
    if (lane == 0) {
        float e = __expf(-GAMMA * acc);
        fac[row] = xW ? e * xW[row] : e;
    }
}

__global__ void init_out(float* __restrict__ out, const float* __restrict__ b, int n) {
    int i = blockIdx.x * blockDim.x + threadIdx.x;
    if (i < n) out[i] = b[0];
}

// ---------------- LDS geometry ----------------
// lA @0: 16 kchunks(32k) x 8 rowblocks(16 rows) x 1024B. Within a 1KB block,
//   granule g = kslot*16 + row' (k-major): holds row (rowBase+rb*16+row'),
//   k = q*32 + kslot*8 .. +7.  Fragment read = block_base + lane*16 (linear!).
// lB @131072: 2 dbuf x 16 colblocks(16 cols) x 1024B, same k-major micro-layout.

// grid: 256 blocks (1/CU), 512 threads (8 waves: 2 row-halves x 4 col-quarters).
__global__ __launch_bounds__(512, 2) void rbf_gemm(
    const __bf16* __restrict__ Xb, const __bf16* __restrict__ Yb,
    const float* __restrict__ ex, const float* __restrict__ cw,
    float* __restrict__ out) {
    __shared__ __align__(128) char smem[163840];

    const int tid  = threadIdx.x;
    const int wid  = tid >> 6;
    const int lane = tid & 63;
    const int wr   = wid >> 2;      // 0..1: row half (64 rows)
    const int wc   = wid & 3;       // 0..3: col quarter (64 cols of the 256-chunk)

    // XCD-aware block map (same as r5: FETCH was compulsory-only with this).
    const int pid = blockIdx.x;
    const int xcd = pid & 7;
    const int j   = pid >> 3;                  // 0..31
    const int ch  = xcd & 1;                   // col half of Y
    const int rg  = (xcd >> 1) * 32 + j;       // 0..127 row group
    const int rowBase = rg * 128;
    const int colBase = ch * 4096;

    const int l15 = lane & 15, l4 = lane >> 4;
    const int lane16 = lane * 16;

    // per-lane gather sources implementing the k-major LDS layout (linear dest)
    const __bf16* sAlane = Xb + (size_t)(rowBase + wid * 16 + l15) * 512 + l4 * 8;
    const __bf16* sBlane = Yb + (size_t)(colBase + l15) * 512 + l4 * 8;

    // ---- prologue: whole A panel (wave wid = rowblock wid, all 16 kchunks)
    //      + B panel0/kchunk0 into dbuf0 (wave wid = colblocks 2wid, 2wid+1)
#pragma unroll
    for (int q = 0; q < 16; ++q)
        __builtin_amdgcn_global_load_lds((gl_void_t*)(sAlane + q * 32),
            (lds_void_t*)(smem + q * 8192 + wid * 1024), 16, 0, 0);
#pragma unroll
    for (int jj = 0; jj < 2; ++jj)
        __builtin_amdgcn_global_load_lds((gl_void_t*)(sBlane + (2 * wid + jj) * 8192),
            (lds_void_t*)(smem + 131072 + (2 * wid + jj) * 1024), 16, 0, 0);
    asm volatile("s_waitcnt vmcnt(0)");
    __builtin_amdgcn_s_barrier();

    f32x4 acc[4][4] = {};
    float rowsum[4][4] = {};
    const int lcol = l15, lrow = l4;

    // ---- main: 16 col-panels x 16 kchunks; acc over k within a panel.
    for (int p = 0; p < 16; ++p) {
#pragma unroll
        for (int q = 0; q < 16; ++q) {
            const int c = p * 16 + q;
            // stage chunk c+1 into the other buffer (issue-early)
            if ((q < 15) || (p < 15)) {
                const int q1 = (q + 1) & 15;
                const int p1 = p + (q == 15);
                const int dstb = 131072 + ((c + 1) & 1) * 16384;
                const __bf16* src = sBlane + (size_t)p1 * 131072 + q1 * 32;
#pragma unroll
                for (int jj = 0; jj < 2; ++jj)
                    __builtin_amdgcn_global_load_lds(
                        (gl_void_t*)(src + (2 * wid + jj) * 8192),
                        (lds_void_t*)(smem + dstb + (2 * wid + jj) * 1024), 16, 0, 0);
            }

            const int aOff = q * 8192 + wr * 4096 + lane16;
            const int bOff = 131072 + (c & 1) * 16384 + wc * 4096 + lane16;
            bf16x8 af[4], bfv[4];
#pragma unroll
            for (int rb = 0; rb < 4; ++rb)
                af[rb] = *reinterpret_cast<const bf16x8*>(&smem[aOff + rb * 1024]);
#pragma unroll
            for (int cb = 0; cb < 4; ++cb)
                bfv[cb] = *reinterpret_cast<const bf16x8*>(&smem[bOff + cb * 1024]);

            __builtin_amdgcn_s_setprio(1);
#pragma unroll
            for (int rb = 0; rb < 4; ++rb)
#pragma unroll
                for (int cb = 0; cb < 4; ++cb)
                    acc[rb][cb] = __builtin_amdgcn_mfma_f32_16x16x32_bf16(
                        af[rb], bfv[cb], acc[rb][cb], 0, 0, 0);
            __builtin_amdgcn_s_setprio(0);

            asm volatile("s_waitcnt vmcnt(0)");   // stage issued at top of iter
            __builtin_amdgcn_s_barrier();
        }

        // ---- per-panel epilogue: pure VALU + 4 cw loads; acc holds full K=512
        float cv[4];
#pragma unroll
        for (int cb = 0; cb < 4; ++cb)
            cv[cb] = cw[colBase + p * 256 + (wc * 4 + cb) * 16 + lcol];
#pragma unroll
        for (int rb = 0; rb < 4; ++rb)
#pragma unroll
            for (int i2 = 0; i2 < 4; ++i2) {
                float s = rowsum[rb][i2];
#pragma unroll
                for (int cb = 0; cb < 4; ++cb)
                    s += __expf(0.004f * acc[rb][cb][i2]) * cv[cb];
                rowsum[rb][i2] = s;
            }
#pragma unroll
        for (int rb = 0; rb < 4; ++rb)
#pragma unroll
            for (int cb = 0; cb < 4; ++cb)
                acc[rb][cb] = (f32x4){0.f, 0.f, 0.f, 0.f};
    }

    // ---- final: 16-lane reduce + one atomic per (col-wave, n); out pre-init'd to b
#pragma unroll
    for (int rb = 0; rb < 4; ++rb)
#pragma unroll
        for (int i2 = 0; i2 < 4; ++i2) {
            float s = rowsum[rb][i2];
#pragma unroll
            for (int off = 1; off < 16; off <<= 1) s += __shfl_xor(s, off, 64);
            if (lcol == 0) {
                const int n = rowBase + wr * 64 + rb * 16 + lrow * 4 + i2;
                atomicAdd(&out[n], ex[n] * s);
            }
        }
}

extern "C" void kernel_launch(void* const* d_in, const int* in_sizes, int n_in,
                              void* d_out, int out_size, void* d_ws, size_t ws_size,
                              hipStream_t stream) {
    const float* X = (const float*)d_in[0];   // 16384 x 512
    const float* Y = (const float*)d_in[1];   //  8192 x 512
    const float* W = (const float*)d_in[2];   // 8192
    const float* b = (const float*)d_in[3];   // 1
    float* out = (float*)d_out;               // 16384

    char* ws = (char*)d_ws;
    __bf16* Xb = (__bf16*)(ws);
    __bf16* Yb = (__bf16*)(ws + 16777216);
    float*  ex = (float*)(ws + 16777216 + 8388608);
    float*  cw = (float*)(ws + 16777216 + 8388608 + 65536);

    prep_kernel<<<4096, 256, 0, stream>>>(X, Xb, ex, nullptr, 16384);
    prep_kernel<<<2048, 256, 0, stream>>>(Y, Yb, cw, W, 8192);
    init_out<<<64, 256, 0, stream>>>(out, b, 16384);
    rbf_gemm<<<256, 512, 0, stream>>>(Xb, Yb, ex, cw, out);
}